// Round 3
// baseline (174.065 us; speedup 1.0000x reference)
//
#include <hip/hip_runtime.h>
#include <stdint.h>

// S=4096, D=64.  out = (t * floor(t*rr)/R) @ V,  t = (QK^T*8) * dropout_keep/0.9
// R3 structure:
//   prep: u -> 2MB keep-bitmask (ballot);  Q->bf16;  K->bf16*(8/0.9);  V->V^T bf16
//   main: NO __syncthreads. All MFMA A/B frags are direct global b128 loads from
//         prepped arrays (L1/L2 hits). Only wave-private LDS for P relayout
//         (C-layout -> A-layout stays within the wave), guarded by
//         s_waitcnt lgkmcnt(0) + wave_barrier. Waves fully independent.

#define S 4096
#define D 64
#define NCHUNK 32             // grid = 64 i-blocks * 32 chunks = 2048 blocks
#define JCHUNK (S / NCHUNK)   // 128
#define NTILES (JCHUNK / 64)  // 2
#define LDP 72                // pb row pitch in shorts (144B: 16B-aligned, 2-way banks)
#define KSCALE (8.0f / 0.9f)

typedef float f32x4 __attribute__((ext_vector_type(4)));
typedef short s16x8 __attribute__((ext_vector_type(8)));
typedef unsigned short u16x4 __attribute__((ext_vector_type(4)));

__device__ inline unsigned short f2bf(float f) {
    union { float f; unsigned u; } v; v.f = f;
    unsigned r = v.u + 0x7fffu + ((v.u >> 16) & 1u);
    return (unsigned short)(r >> 16);
}

// ---- prep 1: pack keep-bits. wave reads 64 consecutive floats, ballot -> 8B ----
#define PM_BLOCKS 1024        // 1024*256/64 = 4096 waves; 262144 groups / 4096 = 64/wave
__global__ void pack_mask(const float* __restrict__ u, unsigned long long* __restrict__ mask) {
    const int gid  = blockIdx.x * 256 + threadIdx.x;
    const int wid  = gid >> 6;
    const int lane = gid & 63;
    const int base = wid * 64;            // 64 groups per wave, contiguous
#pragma unroll
    for (int o = 0; o < 64; o += 4) {
        float v0 = u[(size_t)(base + o + 0) * 64 + lane];
        float v1 = u[(size_t)(base + o + 1) * 64 + lane];
        float v2 = u[(size_t)(base + o + 2) * 64 + lane];
        float v3 = u[(size_t)(base + o + 3) * 64 + lane];
        unsigned long long m0 = __ballot(v0 >= 0.1f);
        unsigned long long m1 = __ballot(v1 >= 0.1f);
        unsigned long long m2 = __ballot(v2 >= 0.1f);
        unsigned long long m3 = __ballot(v3 >= 0.1f);
        if (lane == 0) {
            mask[base + o + 0] = m0;  mask[base + o + 1] = m1;
            mask[base + o + 2] = m2;  mask[base + o + 3] = m3;
        }
    }
}

// ---- prep 2: Q->bf16, K->bf16*KSCALE (512 blocks: first half Q, second half K) ----
__global__ void conv_qk(const float* __restrict__ Q, const float* __restrict__ Kf,
                        short* __restrict__ Qbf, short* __restrict__ Kbf) {
    const int idx = blockIdx.x * 256 + threadIdx.x;   // 131072 threads, 65536 float4 each
    if (idx < 65536) {
        float4 v = ((const float4*)Q)[idx];
        u16x4 o; o[0] = f2bf(v.x); o[1] = f2bf(v.y); o[2] = f2bf(v.z); o[3] = f2bf(v.w);
        ((u16x4*)Qbf)[idx] = o;
    } else {
        const int k = idx - 65536;
        float4 v = ((const float4*)Kf)[k];
        u16x4 o; o[0] = f2bf(v.x * KSCALE); o[1] = f2bf(v.y * KSCALE);
                 o[2] = f2bf(v.z * KSCALE); o[3] = f2bf(v.w * KSCALE);
        ((u16x4*)Kbf)[k] = o;
    }
}

// ---- prep 3: V -> V^T bf16 via LDS tile (64 blocks, 64-row tiles) ----
__global__ void conv_vt(const float* __restrict__ V, short* __restrict__ VTbf) {
    __shared__ short tile[64 * 68];
    const int t  = threadIdx.x;
    const int j0 = blockIdx.x * 64;
#pragma unroll
    for (int it = 0; it < 4; ++it) {
        const int f4 = t + it * 256;
        const int row = f4 >> 4, c4 = (f4 & 15) * 4;
        float4 v = *(const float4*)&V[(size_t)(j0 + row) * D + c4];
        tile[(c4 + 0) * 68 + row] = (short)f2bf(v.x);
        tile[(c4 + 1) * 68 + row] = (short)f2bf(v.y);
        tile[(c4 + 2) * 68 + row] = (short)f2bf(v.z);
        tile[(c4 + 3) * 68 + row] = (short)f2bf(v.w);
    }
    __syncthreads();
#pragma unroll
    for (int it = 0; it < 4; ++it) {
        const int f4 = t + it * 256;
        const int d = f4 >> 4, o4 = (f4 & 15) * 4;
        u16x4 w = *(const u16x4*)&tile[d * 68 + o4];
        *(u16x4*)&VTbf[(size_t)d * S + j0 + o4] = w;
    }
}

// ---- main: barrier-free fused QK^T -> mask/floor -> PV ----
__launch_bounds__(256, 4)
__global__ void fused_main(const short* __restrict__ Qbf,
                           const short* __restrict__ Kbf,
                           const short* __restrict__ VTbf,
                           const unsigned* __restrict__ mask32,  // [S][S/32]
                           const float* __restrict__ RR,
                           float* __restrict__ out,              // pre-zeroed
                           int* __restrict__ sumr)               // pre-zeroed
{
    __shared__ short pb[4 * 16 * LDP];   // wave-private P relayout regions
    __shared__ int red[4];

    const int tid  = threadIdx.x;
    const int w    = tid >> 6;
    const int lane = tid & 63;
    const int quad = lane >> 4;
    const int n16  = lane & 15;

    const int ib  = blockIdx.x & 63;
    const int ic  = blockIdx.x >> 6;
    const int i0w = ib * 64 + w * 16;

    // A-frags for Q: direct contiguous b128 loads
    s16x8 aQ[2];
#pragma unroll
    for (int ks = 0; ks < 2; ++ks)
        aQ[ks] = *(const s16x8*)&Qbf[(size_t)(i0w + n16) * D + ks * 32 + quad * 8];

    float rr[4];
#pragma unroll
    for (int rg = 0; rg < 4; ++rg) rr[rg] = RR[i0w + quad * 4 + rg];

    f32x4 accO[4];
#pragma unroll
    for (int ds = 0; ds < 4; ++ds) accO[ds] = (f32x4){0.f, 0.f, 0.f, 0.f};

    int lsum = 0;
    short* pw = pb + w * 16 * LDP;

#pragma unroll
    for (int jt = 0; jt < NTILES; ++jt) {
        const int j0 = ic * JCHUNK + jt * 64;

        // QK^T: B-frags straight from global (16 consecutive rows, 16B/lane)
        f32x4 accqk[4];
#pragma unroll
        for (int cs = 0; cs < 4; ++cs) {
            f32x4 acc = (f32x4){0.f, 0.f, 0.f, 0.f};
#pragma unroll
            for (int ks = 0; ks < 2; ++ks) {
                s16x8 bK = *(const s16x8*)&Kbf[(size_t)(j0 + cs * 16 + n16) * D + ks * 32 + quad * 8];
                acc = __builtin_amdgcn_mfma_f32_16x16x32_bf16(aQ[ks], bK, acc, 0, 0, 0);
            }
            accqk[cs] = acc;
        }

        // keep-masks: 8B broadcast load per row (quad-uniform address)
        uint2 mrow[4];
#pragma unroll
        for (int rg = 0; rg < 4; ++rg)
            mrow[rg] = *(const uint2*)&mask32[(size_t)(i0w + quad * 4 + rg) * (S / 32) + (j0 >> 5)];

        // epilogue: dropout bit + floor mask; p -> wave-private LDS (A-layout rows)
#pragma unroll
        for (int cs = 0; cs < 4; ++cs) {
            const unsigned bitpos = ((unsigned)(cs & 1) << 4) + (unsigned)n16;
#pragma unroll
            for (int rg = 0; rg < 4; ++rg) {
                const unsigned bits = (cs < 2) ? mrow[rg].x : mrow[rg].y;
                const float t = ((bits >> bitpos) & 1u) ? accqk[cs][rg] : 0.0f;  // KSCALE folded in Kbf
                const float r = floorf(t * rr[rg]);
                lsum += (int)r;
                pw[(quad * 4 + rg) * LDP + cs * 16 + n16] = (short)f2bf(t * r);
            }
        }

        // within-wave visibility: drain LDS writes; no block barrier needed
        __builtin_amdgcn_wave_barrier();
        __asm__ volatile("s_waitcnt lgkmcnt(0)" ::: "memory");
        __builtin_amdgcn_wave_barrier();

        // PV: A from wave-private LDS, B straight from global V^T
#pragma unroll
        for (int ksj = 0; ksj < 2; ++ksj) {
            s16x8 aP = *(const s16x8*)&pw[n16 * LDP + ksj * 32 + quad * 8];
#pragma unroll
            for (int ds = 0; ds < 4; ++ds) {
                s16x8 bV = *(const s16x8*)&VTbf[(size_t)(ds * 16 + n16) * S + j0 + ksj * 32 + quad * 8];
                accO[ds] = __builtin_amdgcn_mfma_f32_16x16x32_bf16(aP, bV, accO[ds], 0, 0, 0);
            }
        }
        // keep next tile's pb writes behind this tile's reads
        __builtin_amdgcn_wave_barrier();
    }

    // numerator partials: fp32 atomics (NCHUNK-way per address, spread over 256K addrs)
#pragma unroll
    for (int ds = 0; ds < 4; ++ds) {
        const int d = ds * 16 + n16;
#pragma unroll
        for (int rg = 0; rg < 4; ++rg) {
            const int i = i0w + quad * 4 + rg;
            unsafeAtomicAdd(&out[(size_t)i * D + d], accO[ds][rg]);
        }
    }

    // sum(r): wave shuffle -> LDS -> one int atomic per block
    for (int off = 32; off; off >>= 1) lsum += __shfl_down(lsum, off);
    if (lane == 0) red[w] = lsum;
    __syncthreads();
    if (tid == 0) atomicAdd(sumr, red[0] + red[1] + red[2] + red[3]);
}

__global__ void scale_kernel(float* __restrict__ out, const int* __restrict__ sumr) {
    const int idx = blockIdx.x * blockDim.x + threadIdx.x;
    const float invR = 1.0f / (float)(*sumr);   // |R| < 2^24: exact
    if (idx < S * D) out[idx] *= invR;
}

extern "C" void kernel_launch(void* const* d_in, const int* in_sizes, int n_in,
                              void* d_out, int out_size, void* d_ws, size_t ws_size,
                              hipStream_t stream) {
    (void)in_sizes; (void)n_in; (void)out_size; (void)ws_size;
    const float* Q  = (const float*)d_in[0];
    const float* Kf = (const float*)d_in[1];
    const float* V  = (const float*)d_in[2];
    const float* Ud = (const float*)d_in[3];
    const float* RR = (const float*)d_in[4];
    float* out = (float*)d_out;

    // ws layout: mask 2MB | Qbf 512KB | Kbf 512KB | VTbf 512KB | sumr
    char* ws = (char*)d_ws;
    unsigned long long* mask = (unsigned long long*)ws;            // 2 MB
    short* Qbf  = (short*)(ws + (2u << 20));                       // 512 KB
    short* Kbf  = (short*)(ws + (2u << 20) + (512u << 10));        // 512 KB
    short* VTbf = (short*)(ws + (2u << 20) + (1024u << 10));       // 512 KB
    int*   sumr = (int*)  (ws + (2u << 20) + (1536u << 10));

    hipMemsetAsync(d_out, 0, (size_t)S * D * sizeof(float), stream);
    hipMemsetAsync(sumr, 0, sizeof(int), stream);
    pack_mask<<<dim3(PM_BLOCKS), dim3(256), 0, stream>>>(Ud, mask);
    conv_qk  <<<dim3(512), dim3(256), 0, stream>>>(Q, Kf, Qbf, Kbf);
    conv_vt  <<<dim3(64),  dim3(256), 0, stream>>>(V, VTbf);
    fused_main<<<dim3(64 * NCHUNK), dim3(256), 0, stream>>>(
        Qbf, Kbf, VTbf, (const unsigned*)mask, RR, out, sumr);
    scale_kernel<<<dim3((S * D) / 256), dim3(256), 0, stream>>>(out, sumr);
}

// Round 4
// 166.798 us; speedup vs baseline: 1.0436x; 1.0436x over previous
//
#include <hip/hip_runtime.h>
#include <stdint.h>

// S=4096, D=64.  out = (t * floor(t*rr)/R) @ V,  t = (QK^T*8) * dropout_keep/0.9
// R4: R3's barrier-free structure, but output atomics (8.4M 4B RMWs — the
// hypothesized 43K-cycle/block stall source) replaced with deterministic
// per-chunk partial stores + a reduce kernel that also applies 1/R.

#define S 4096
#define D 64
#define NCHUNK 32             // grid = 64 i-blocks * 32 chunks = 2048 blocks
#define JCHUNK (S / NCHUNK)   // 128
#define NTILES (JCHUNK / 64)  // 2
#define LDP 72                // pb row pitch in shorts
#define KSCALE (8.0f / 0.9f)

typedef float f32x4 __attribute__((ext_vector_type(4)));
typedef short s16x8 __attribute__((ext_vector_type(8)));
typedef unsigned short u16x4 __attribute__((ext_vector_type(4)));

__device__ inline unsigned short f2bf(float f) {
    union { float f; unsigned u; } v; v.f = f;
    unsigned r = v.u + 0x7fffu + ((v.u >> 16) & 1u);
    return (unsigned short)(r >> 16);
}

// ---- prep 1: pack keep-bits (64MB stream, HBM-bound) ----
#define PM_BLOCKS 1024
__global__ void pack_mask(const float* __restrict__ u, unsigned long long* __restrict__ mask) {
    const int gid  = blockIdx.x * 256 + threadIdx.x;
    const int wid  = gid >> 6;
    const int lane = gid & 63;
    const int base = wid * 64;
#pragma unroll
    for (int o = 0; o < 64; o += 4) {
        float v0 = u[(size_t)(base + o + 0) * 64 + lane];
        float v1 = u[(size_t)(base + o + 1) * 64 + lane];
        float v2 = u[(size_t)(base + o + 2) * 64 + lane];
        float v3 = u[(size_t)(base + o + 3) * 64 + lane];
        unsigned long long m0 = __ballot(v0 >= 0.1f);
        unsigned long long m1 = __ballot(v1 >= 0.1f);
        unsigned long long m2 = __ballot(v2 >= 0.1f);
        unsigned long long m3 = __ballot(v3 >= 0.1f);
        if (lane == 0) {
            mask[base + o + 0] = m0;  mask[base + o + 1] = m1;
            mask[base + o + 2] = m2;  mask[base + o + 3] = m3;
        }
    }
}

// ---- prep 2: Q->bf16, K->bf16*KSCALE ----
__global__ void conv_qk(const float* __restrict__ Q, const float* __restrict__ Kf,
                        short* __restrict__ Qbf, short* __restrict__ Kbf) {
    const int idx = blockIdx.x * 256 + threadIdx.x;
    if (idx < 65536) {
        float4 v = ((const float4*)Q)[idx];
        u16x4 o; o[0] = f2bf(v.x); o[1] = f2bf(v.y); o[2] = f2bf(v.z); o[3] = f2bf(v.w);
        ((u16x4*)Qbf)[idx] = o;
    } else {
        const int k = idx - 65536;
        float4 v = ((const float4*)Kf)[k];
        u16x4 o; o[0] = f2bf(v.x * KSCALE); o[1] = f2bf(v.y * KSCALE);
                 o[2] = f2bf(v.z * KSCALE); o[3] = f2bf(v.w * KSCALE);
        ((u16x4*)Kbf)[k] = o;
    }
}

// ---- prep 3: V -> V^T bf16 ----
__global__ void conv_vt(const float* __restrict__ V, short* __restrict__ VTbf) {
    __shared__ short tile[64 * 68];
    const int t  = threadIdx.x;
    const int j0 = blockIdx.x * 64;
#pragma unroll
    for (int it = 0; it < 4; ++it) {
        const int f4 = t + it * 256;
        const int row = f4 >> 4, c4 = (f4 & 15) * 4;
        float4 v = *(const float4*)&V[(size_t)(j0 + row) * D + c4];
        tile[(c4 + 0) * 68 + row] = (short)f2bf(v.x);
        tile[(c4 + 1) * 68 + row] = (short)f2bf(v.y);
        tile[(c4 + 2) * 68 + row] = (short)f2bf(v.z);
        tile[(c4 + 3) * 68 + row] = (short)f2bf(v.w);
    }
    __syncthreads();
#pragma unroll
    for (int it = 0; it < 4; ++it) {
        const int f4 = t + it * 256;
        const int d = f4 >> 4, o4 = (f4 & 15) * 4;
        u16x4 w = *(const u16x4*)&tile[d * 68 + o4];
        *(u16x4*)&VTbf[(size_t)d * S + j0 + o4] = w;
    }
}

// ---- main: barrier-free fused QK^T -> mask/floor -> PV; plain partial stores ----
__launch_bounds__(256, 4)
__global__ void fused_main(const short* __restrict__ Qbf,
                           const short* __restrict__ Kbf,
                           const short* __restrict__ VTbf,
                           const unsigned* __restrict__ mask32,  // [S][S/32]
                           const float* __restrict__ RR,
                           float* __restrict__ Opart,            // [NCHUNK][S][D]
                           int* __restrict__ sumr)               // pre-zeroed
{
    __shared__ short pb[4 * 16 * LDP];
    __shared__ int red[4];

    const int tid  = threadIdx.x;
    const int w    = tid >> 6;
    const int lane = tid & 63;
    const int quad = lane >> 4;
    const int n16  = lane & 15;

    const int ib  = blockIdx.x & 63;
    const int ic  = blockIdx.x >> 6;
    const int i0w = ib * 64 + w * 16;

    s16x8 aQ[2];
#pragma unroll
    for (int ks = 0; ks < 2; ++ks)
        aQ[ks] = *(const s16x8*)&Qbf[(size_t)(i0w + n16) * D + ks * 32 + quad * 8];

    float rr[4];
#pragma unroll
    for (int rg = 0; rg < 4; ++rg) rr[rg] = RR[i0w + quad * 4 + rg];

    f32x4 accO[4];
#pragma unroll
    for (int ds = 0; ds < 4; ++ds) accO[ds] = (f32x4){0.f, 0.f, 0.f, 0.f};

    int lsum = 0;
    short* pw = pb + w * 16 * LDP;

#pragma unroll
    for (int jt = 0; jt < NTILES; ++jt) {
        const int j0 = ic * JCHUNK + jt * 64;

        // QK^T: B-frags straight from global
        f32x4 accqk[4];
#pragma unroll
        for (int cs = 0; cs < 4; ++cs) {
            f32x4 acc = (f32x4){0.f, 0.f, 0.f, 0.f};
#pragma unroll
            for (int ks = 0; ks < 2; ++ks) {
                s16x8 bK = *(const s16x8*)&Kbf[(size_t)(j0 + cs * 16 + n16) * D + ks * 32 + quad * 8];
                acc = __builtin_amdgcn_mfma_f32_16x16x32_bf16(aQ[ks], bK, acc, 0, 0, 0);
            }
            accqk[cs] = acc;
        }

        // keep-masks: 8B broadcast loads
        uint2 mrow[4];
#pragma unroll
        for (int rg = 0; rg < 4; ++rg)
            mrow[rg] = *(const uint2*)&mask32[(size_t)(i0w + quad * 4 + rg) * (S / 32) + (j0 >> 5)];

        // epilogue: dropout bit + floor mask; p -> wave-private LDS
#pragma unroll
        for (int cs = 0; cs < 4; ++cs) {
            const unsigned bitpos = ((unsigned)(cs & 1) << 4) + (unsigned)n16;
#pragma unroll
            for (int rg = 0; rg < 4; ++rg) {
                const unsigned bits = (cs < 2) ? mrow[rg].x : mrow[rg].y;
                const float t = ((bits >> bitpos) & 1u) ? accqk[cs][rg] : 0.0f;
                const float r = floorf(t * rr[rg]);
                lsum += (int)r;
                pw[(quad * 4 + rg) * LDP + cs * 16 + n16] = (short)f2bf(t * r);
            }
        }

        __builtin_amdgcn_wave_barrier();
        __asm__ volatile("s_waitcnt lgkmcnt(0)" ::: "memory");
        __builtin_amdgcn_wave_barrier();

        // PV: A from wave-private LDS, B straight from global V^T
#pragma unroll
        for (int ksj = 0; ksj < 2; ++ksj) {
            s16x8 aP = *(const s16x8*)&pw[n16 * LDP + ksj * 32 + quad * 8];
#pragma unroll
            for (int ds = 0; ds < 4; ++ds) {
                s16x8 bV = *(const s16x8*)&VTbf[(size_t)(ds * 16 + n16) * S + j0 + ksj * 32 + quad * 8];
                accO[ds] = __builtin_amdgcn_mfma_f32_16x16x32_bf16(aP, bV, accO[ds], 0, 0, 0);
            }
        }
        __builtin_amdgcn_wave_barrier();
    }

    // deterministic partial stores: each (ic,i,d) written exactly once,
    // each store instr covers full 64B lines (16 lanes/row x 4 rows)
    float* op = Opart + (size_t)ic * S * D;
#pragma unroll
    for (int ds = 0; ds < 4; ++ds) {
        const int d = ds * 16 + n16;
#pragma unroll
        for (int rg = 0; rg < 4; ++rg) {
            const int i = i0w + quad * 4 + rg;
            op[(size_t)i * D + d] = accO[ds][rg];
        }
    }

    // sum(r): wave shuffle -> LDS -> one int atomic per block (2048 total)
    for (int off = 32; off; off >>= 1) lsum += __shfl_down(lsum, off);
    if (lane == 0) red[w] = lsum;
    __syncthreads();
    if (tid == 0) atomicAdd(sumr, red[0] + red[1] + red[2] + red[3]);
}

// ---- reduce partials over NCHUNK + apply 1/R (deterministic order) ----
__global__ void reduce_out(const float* __restrict__ Opart,
                           const int* __restrict__ sumr,
                           float* __restrict__ out) {
    const int idx = blockIdx.x * 256 + threadIdx.x;   // 65536 float4 groups
    const float invR = 1.0f / (float)(*sumr);         // |R| < 2^24: exact
    float sx = 0.f, sy = 0.f, sz = 0.f, sw = 0.f;
#pragma unroll 8
    for (int c = 0; c < NCHUNK; ++c) {
        const float4 v = ((const float4*)(Opart + (size_t)c * S * D))[idx];
        sx += v.x; sy += v.y; sz += v.z; sw += v.w;
    }
    float4 o; o.x = sx * invR; o.y = sy * invR; o.z = sz * invR; o.w = sw * invR;
    ((float4*)out)[idx] = o;
}

extern "C" void kernel_launch(void* const* d_in, const int* in_sizes, int n_in,
                              void* d_out, int out_size, void* d_ws, size_t ws_size,
                              hipStream_t stream) {
    (void)in_sizes; (void)n_in; (void)out_size; (void)ws_size;
    const float* Q  = (const float*)d_in[0];
    const float* Kf = (const float*)d_in[1];
    const float* V  = (const float*)d_in[2];
    const float* Ud = (const float*)d_in[3];
    const float* RR = (const float*)d_in[4];
    float* out = (float*)d_out;

    // ws layout: Opart 32MB | mask 2MB | Qbf 512KB | Kbf 512KB | VTbf 512KB | sumr
    char* ws = (char*)d_ws;
    float* Opart = (float*)ws;                                      // 32 MB
    unsigned long long* mask = (unsigned long long*)(ws + (32u << 20)); // 2 MB
    short* Qbf  = (short*)(ws + (34u << 20));
    short* Kbf  = (short*)(ws + (34u << 20) + (512u << 10));
    short* VTbf = (short*)(ws + (34u << 20) + (1024u << 10));
    int*   sumr = (int*)  (ws + (34u << 20) + (1536u << 10));

    hipMemsetAsync(sumr, 0, sizeof(int), stream);
    pack_mask<<<dim3(PM_BLOCKS), dim3(256), 0, stream>>>(Ud, mask);
    conv_qk  <<<dim3(512), dim3(256), 0, stream>>>(Q, Kf, Qbf, Kbf);
    conv_vt  <<<dim3(64),  dim3(256), 0, stream>>>(V, VTbf);
    fused_main<<<dim3(64 * NCHUNK), dim3(256), 0, stream>>>(
        Qbf, Kbf, VTbf, (const unsigned*)mask, RR, Opart, sumr);
    reduce_out<<<dim3(256), dim3(256), 0, stream>>>(Opart, sumr, out);
}

// Round 5
// 147.207 us; speedup vs baseline: 1.1824x; 1.1331x over previous
//
#include <hip/hip_runtime.h>
#include <stdint.h>

// S=4096, D=64.  out = (t * floor(t*rr)/R) @ V,  t = (QK^T*8) * dropout_keep/0.9
// R5: attack memory-level parallelism. Four prior structures all hit a ~55us
// floor == ~2000 loads/CU x ~600cyc / ~10 in flight. Fix: register
// double-buffered software pipeline, ~17 b128 loads outstanding per wave
// (launch_bounds(256,2) -> ~200 VGPR budget). Also: single fused prep kernel,
// no memsets -> 3 dispatches total.

#define S 4096
#define D 64
#define NCHUNK 16             // grid = 64 i-blocks * 16 chunks = 1024 blocks
#define JCHUNK (S / NCHUNK)   // 256
#define NTILES (JCHUNK / 64)  // 4 j-tiles of 64 per block
#define LDP 72                // pb row pitch in shorts
#define KSCALE (8.0f / 0.9f)

typedef float f32x4 __attribute__((ext_vector_type(4)));
typedef short s16x8 __attribute__((ext_vector_type(8)));
typedef unsigned short u16x4 __attribute__((ext_vector_type(4)));

__device__ inline unsigned short f2bf(float f) {
    union { float f; unsigned u; } v; v.f = f;
    unsigned r = v.u + 0x7fffu + ((v.u >> 16) & 1u);
    return (unsigned short)(r >> 16);
}

// ---- prep: ONE kernel, branch by block range ----
//   blocks [0,1024):    u -> keep-bitmask (64MB stream, HBM-bound)
//   blocks [1024,1536): Q->bf16, K->bf16*KSCALE
//   blocks [1536,1600): V -> V^T bf16
__global__ void prep_all(const float* __restrict__ u,
                         const float* __restrict__ Q,
                         const float* __restrict__ Kf,
                         const float* __restrict__ V,
                         unsigned long long* __restrict__ mask,
                         short* __restrict__ Qbf, short* __restrict__ Kbf,
                         short* __restrict__ VTbf, int* __restrict__ sumr) {
    __shared__ short tile[64 * 68];
    const int b   = blockIdx.x;
    const int tid = threadIdx.x;
    if (b == 0 && tid == 0) *sumr = 0;   // replaces a memset dispatch

    if (b < 1024) {
        const int gid  = b * 256 + tid;
        const int wid  = gid >> 6;
        const int lane = gid & 63;
        const int base = wid * 64;        // 64 groups of 64 floats per wave
#pragma unroll
        for (int o = 0; o < 64; o += 4) {
            float v0 = u[(size_t)(base + o + 0) * 64 + lane];
            float v1 = u[(size_t)(base + o + 1) * 64 + lane];
            float v2 = u[(size_t)(base + o + 2) * 64 + lane];
            float v3 = u[(size_t)(base + o + 3) * 64 + lane];
            unsigned long long m0 = __ballot(v0 >= 0.1f);
            unsigned long long m1 = __ballot(v1 >= 0.1f);
            unsigned long long m2 = __ballot(v2 >= 0.1f);
            unsigned long long m3 = __ballot(v3 >= 0.1f);
            if (lane == 0) {
                mask[base + o + 0] = m0;  mask[base + o + 1] = m1;
                mask[base + o + 2] = m2;  mask[base + o + 3] = m3;
            }
        }
    } else if (b < 1536) {
        const int idx = (b - 1024) * 256 + tid;      // 131072 float4 slots
        if (idx < 65536) {
            float4 v = ((const float4*)Q)[idx];
            u16x4 o; o[0] = f2bf(v.x); o[1] = f2bf(v.y); o[2] = f2bf(v.z); o[3] = f2bf(v.w);
            ((u16x4*)Qbf)[idx] = o;
        } else {
            const int k = idx - 65536;
            float4 v = ((const float4*)Kf)[k];
            u16x4 o; o[0] = f2bf(v.x * KSCALE); o[1] = f2bf(v.y * KSCALE);
                     o[2] = f2bf(v.z * KSCALE); o[3] = f2bf(v.w * KSCALE);
            ((u16x4*)Kbf)[k] = o;
        }
    } else {
        const int j0 = (b - 1536) * 64;
#pragma unroll
        for (int it = 0; it < 4; ++it) {
            const int f4 = tid + it * 256;
            const int row = f4 >> 4, c4 = (f4 & 15) * 4;
            float4 v = *(const float4*)&V[(size_t)(j0 + row) * D + c4];
            tile[(c4 + 0) * 68 + row] = (short)f2bf(v.x);
            tile[(c4 + 1) * 68 + row] = (short)f2bf(v.y);
            tile[(c4 + 2) * 68 + row] = (short)f2bf(v.z);
            tile[(c4 + 3) * 68 + row] = (short)f2bf(v.w);
        }
        __syncthreads();
#pragma unroll
        for (int it = 0; it < 4; ++it) {
            const int f4 = tid + it * 256;
            const int d = f4 >> 4, o4 = (f4 & 15) * 4;
            u16x4 w = *(const u16x4*)&tile[d * 68 + o4];
            *(u16x4*)&VTbf[(size_t)d * S + j0 + o4] = w;
        }
    }
}

// ---- main: barrier-free, register double-buffered pipeline ----
__launch_bounds__(256, 2)
__global__ void fused_main(const short* __restrict__ Qbf,
                           const short* __restrict__ Kbf,
                           const short* __restrict__ VTbf,
                           const unsigned* __restrict__ mask32,  // [S][S/32]
                           const float* __restrict__ RR,
                           float* __restrict__ Opart,            // [NCHUNK][S][D]
                           int* __restrict__ sumr)
{
    __shared__ short pb[4 * 16 * LDP];
    __shared__ int red[4];

    const int tid  = threadIdx.x;
    const int w    = tid >> 6;
    const int lane = tid & 63;
    const int quad = lane >> 4;
    const int n16  = lane & 15;

    const int ib  = blockIdx.x & 63;
    const int ic  = blockIdx.x >> 6;
    const int i0w = ib * 64 + w * 16;
    const int jbase = ic * JCHUNK;

    s16x8 aQ[2];
#pragma unroll
    for (int ks = 0; ks < 2; ++ks)
        aQ[ks] = *(const s16x8*)&Qbf[(size_t)(i0w + n16) * D + ks * 32 + quad * 8];

    float rr[4];
#pragma unroll
    for (int rg = 0; rg < 4; ++rg) rr[rg] = RR[i0w + quad * 4 + rg];

    f32x4 accO[4];
#pragma unroll
    for (int ds = 0; ds < 4; ++ds) accO[ds] = (f32x4){0.f, 0.f, 0.f, 0.f};

    int lsum = 0;
    short* pw = pb + w * 16 * LDP;

    // register double buffers: entire next tile's operands stay in flight
    s16x8 kf[2][8];      // K-frags  [buf][cs*2+ks]
    s16x8 vf[2][8];      // V-frags  [buf][ksj*4+ds]
    uint2 mrow[2][4];    // keep-mask bits per output row

    // prefetch tile 0
#pragma unroll
    for (int e = 0; e < 8; ++e) {
        const int cs = e >> 1, ks = e & 1;
        kf[0][e] = *(const s16x8*)&Kbf[(size_t)(jbase + cs * 16 + n16) * D + ks * 32 + quad * 8];
    }
#pragma unroll
    for (int e = 0; e < 8; ++e) {
        const int ksj = e >> 2, ds = e & 3;
        vf[0][e] = *(const s16x8*)&VTbf[(size_t)(ds * 16 + n16) * S + jbase + ksj * 32 + quad * 8];
    }
#pragma unroll
    for (int rg = 0; rg < 4; ++rg)
        mrow[0][rg] = *(const uint2*)&mask32[(size_t)(i0w + quad * 4 + rg) * (S / 32) + (jbase >> 5)];

#pragma unroll
    for (int jt = 0; jt < NTILES; ++jt) {
        const int bu = jt & 1;
        const int j0 = jbase + jt * 64;

        // issue next tile's loads BEFORE touching this tile's data
        if (jt + 1 < NTILES) {
            const int nb = (jt + 1) & 1;
            const int j1 = j0 + 64;
#pragma unroll
            for (int e = 0; e < 8; ++e) {
                const int cs = e >> 1, ks = e & 1;
                kf[nb][e] = *(const s16x8*)&Kbf[(size_t)(j1 + cs * 16 + n16) * D + ks * 32 + quad * 8];
            }
#pragma unroll
            for (int e = 0; e < 8; ++e) {
                const int ksj = e >> 2, ds = e & 3;
                vf[nb][e] = *(const s16x8*)&VTbf[(size_t)(ds * 16 + n16) * S + j1 + ksj * 32 + quad * 8];
            }
#pragma unroll
            for (int rg = 0; rg < 4; ++rg)
                mrow[nb][rg] = *(const uint2*)&mask32[(size_t)(i0w + quad * 4 + rg) * (S / 32) + (j1 >> 5)];
        }

        // QK^T on current buffer
        f32x4 accqk[4];
#pragma unroll
        for (int cs = 0; cs < 4; ++cs) {
            f32x4 acc = (f32x4){0.f, 0.f, 0.f, 0.f};
#pragma unroll
            for (int ks = 0; ks < 2; ++ks)
                acc = __builtin_amdgcn_mfma_f32_16x16x32_bf16(aQ[ks], kf[bu][cs * 2 + ks], acc, 0, 0, 0);
            accqk[cs] = acc;
        }

        // epilogue: dropout bit + floor mask; p -> wave-private LDS
#pragma unroll
        for (int cs = 0; cs < 4; ++cs) {
            const unsigned bitpos = ((unsigned)(cs & 1) << 4) + (unsigned)n16;
#pragma unroll
            for (int rg = 0; rg < 4; ++rg) {
                const unsigned bits = (cs < 2) ? mrow[bu][rg].x : mrow[bu][rg].y;
                const float t = ((bits >> bitpos) & 1u) ? accqk[cs][rg] : 0.0f;  // KSCALE folded in Kbf
                const float r = floorf(t * rr[rg]);
                lsum += (int)r;
                pw[(quad * 4 + rg) * LDP + cs * 16 + n16] = (short)f2bf(t * r);
            }
        }

        __builtin_amdgcn_wave_barrier();
        __asm__ volatile("s_waitcnt lgkmcnt(0)" ::: "memory");
        __builtin_amdgcn_wave_barrier();

        // PV on current buffer
#pragma unroll
        for (int ksj = 0; ksj < 2; ++ksj) {
            s16x8 aP = *(const s16x8*)&pw[n16 * LDP + ksj * 32 + quad * 8];
#pragma unroll
            for (int ds = 0; ds < 4; ++ds)
                accO[ds] = __builtin_amdgcn_mfma_f32_16x16x32_bf16(aP, vf[bu][ksj * 4 + ds], accO[ds], 0, 0, 0);
        }
        __builtin_amdgcn_wave_barrier();   // pb reuse fence
    }

    // deterministic partial stores (full 64B segments)
    float* op = Opart + (size_t)ic * S * D;
#pragma unroll
    for (int ds = 0; ds < 4; ++ds) {
        const int d = ds * 16 + n16;
#pragma unroll
        for (int rg = 0; rg < 4; ++rg) {
            const int i = i0w + quad * 4 + rg;
            op[(size_t)i * D + d] = accO[ds][rg];
        }
    }

    // sum(r): wave shuffle -> LDS -> one int atomic per block (1024 total)
    for (int off = 32; off; off >>= 1) lsum += __shfl_down(lsum, off);
    if (lane == 0) red[w] = lsum;
    __syncthreads();
    if (tid == 0) atomicAdd(sumr, red[0] + red[1] + red[2] + red[3]);
}

// ---- reduce partials over NCHUNK + apply 1/R ----
__global__ void reduce_out(const float* __restrict__ Opart,
                           const int* __restrict__ sumr,
                           float* __restrict__ out) {
    const int idx = blockIdx.x * 256 + threadIdx.x;   // 65536 float4 groups
    const float invR = 1.0f / (float)(*sumr);         // |R| < 2^24: exact
    float sx = 0.f, sy = 0.f, sz = 0.f, sw = 0.f;
#pragma unroll
    for (int c = 0; c < NCHUNK; ++c) {
        const float4 v = ((const float4*)(Opart + (size_t)c * S * D))[idx];
        sx += v.x; sy += v.y; sz += v.z; sw += v.w;
    }
    float4 o; o.x = sx * invR; o.y = sy * invR; o.z = sz * invR; o.w = sw * invR;
    ((float4*)out)[idx] = o;
}

extern "C" void kernel_launch(void* const* d_in, const int* in_sizes, int n_in,
                              void* d_out, int out_size, void* d_ws, size_t ws_size,
                              hipStream_t stream) {
    (void)in_sizes; (void)n_in; (void)out_size; (void)ws_size;
    const float* Q  = (const float*)d_in[0];
    const float* Kf = (const float*)d_in[1];
    const float* V  = (const float*)d_in[2];
    const float* Ud = (const float*)d_in[3];
    const float* RR = (const float*)d_in[4];
    float* out = (float*)d_out;

    // ws layout: Opart 16MB | mask 2MB | Qbf 512KB | Kbf 512KB | VTbf 512KB | sumr
    char* ws = (char*)d_ws;
    float* Opart = (float*)ws;                                          // 16 MB
    unsigned long long* mask = (unsigned long long*)(ws + (16u << 20)); // 2 MB
    short* Qbf  = (short*)(ws + (18u << 20));
    short* Kbf  = (short*)(ws + (18u << 20) + (512u << 10));
    short* VTbf = (short*)(ws + (18u << 20) + (1024u << 10));
    int*   sumr = (int*)  (ws + (18u << 20) + (1536u << 10));

    prep_all<<<dim3(1600), dim3(256), 0, stream>>>(Ud, Q, Kf, V, mask, Qbf, Kbf, VTbf, sumr);
    fused_main<<<dim3(64 * NCHUNK), dim3(256), 0, stream>>>(
        Qbf, Kbf, VTbf, (const unsigned*)mask, RR, Opart, sumr);
    reduce_out<<<dim3(256), dim3(256), 0, stream>>>(Opart, sumr, out);
}

// Round 6
// 143.505 us; speedup vs baseline: 1.2129x; 1.0258x over previous
//
#include <hip/hip_runtime.h>
#include <stdint.h>

// S=4096, D=64.  out = (t * floor(t*rr)/R) @ V,  t = (QK^T*8) * dropout_keep/0.9
// R6: u_drop read DIRECTLY in fused_main (each element used exactly once ->
// the bitmask prep was a serial 11us HBM prefix with zero reuse benefit).
// u loads are per-lane dwords in C-layout positions, double-buffered one tile
// ahead, nontemporal (don't evict L2-resident K/V/Opart). K-frags double-
// buffered, V-frags single-buffered (in-tile slack covers them). Prep is now
// only Q/K/V bf16 conversion (~3MB).

#define S 4096
#define D 64
#define NCHUNK 16             // grid = 64 i-blocks * 16 chunks = 1024 blocks
#define JCHUNK (S / NCHUNK)   // 256
#define NTILES (JCHUNK / 64)  // 4
#define LDP 72                // pb row pitch in shorts
#define KSCALE (8.0f / 0.9f)

typedef float f32x4 __attribute__((ext_vector_type(4)));
typedef short s16x8 __attribute__((ext_vector_type(8)));
typedef unsigned short u16x4 __attribute__((ext_vector_type(4)));

__device__ inline unsigned short f2bf(float f) {
    union { float f; unsigned u; } v; v.f = f;
    unsigned r = v.u + 0x7fffu + ((v.u >> 16) & 1u);
    return (unsigned short)(r >> 16);
}

// ---- prep: Q->bf16, K->bf16*KSCALE (blocks 0..511), V->V^T (512..575) ----
__global__ void prep_all(const float* __restrict__ Q,
                         const float* __restrict__ Kf,
                         const float* __restrict__ V,
                         short* __restrict__ Qbf, short* __restrict__ Kbf,
                         short* __restrict__ VTbf, int* __restrict__ sumr) {
    __shared__ short tile[64 * 68];
    const int b   = blockIdx.x;
    const int tid = threadIdx.x;
    if (b == 0 && tid == 0) *sumr = 0;

    if (b < 512) {
        const int idx = b * 256 + tid;               // 131072 float4 slots
        if (idx < 65536) {
            float4 v = ((const float4*)Q)[idx];
            u16x4 o; o[0] = f2bf(v.x); o[1] = f2bf(v.y); o[2] = f2bf(v.z); o[3] = f2bf(v.w);
            ((u16x4*)Qbf)[idx] = o;
        } else {
            const int k = idx - 65536;
            float4 v = ((const float4*)Kf)[k];
            u16x4 o; o[0] = f2bf(v.x * KSCALE); o[1] = f2bf(v.y * KSCALE);
                     o[2] = f2bf(v.z * KSCALE); o[3] = f2bf(v.w * KSCALE);
            ((u16x4*)Kbf)[k] = o;
        }
    } else {
        const int j0 = (b - 512) * 64;
#pragma unroll
        for (int it = 0; it < 4; ++it) {
            const int f4 = tid + it * 256;
            const int row = f4 >> 4, c4 = (f4 & 15) * 4;
            float4 v = *(const float4*)&V[(size_t)(j0 + row) * D + c4];
            tile[(c4 + 0) * 68 + row] = (short)f2bf(v.x);
            tile[(c4 + 1) * 68 + row] = (short)f2bf(v.y);
            tile[(c4 + 2) * 68 + row] = (short)f2bf(v.z);
            tile[(c4 + 3) * 68 + row] = (short)f2bf(v.w);
        }
        __syncthreads();
#pragma unroll
        for (int it = 0; it < 4; ++it) {
            const int f4 = tid + it * 256;
            const int d = f4 >> 4, o4 = (f4 & 15) * 4;
            u16x4 w = *(const u16x4*)&tile[d * 68 + o4];
            *(u16x4*)&VTbf[(size_t)d * S + j0 + o4] = w;
        }
    }
}

// ---- main: barrier-free, register-pipelined, direct nontemporal u reads ----
__launch_bounds__(256, 2)
__global__ void fused_main(const short* __restrict__ Qbf,
                           const short* __restrict__ Kbf,
                           const short* __restrict__ VTbf,
                           const float* __restrict__ Ud,
                           const float* __restrict__ RR,
                           float* __restrict__ Opart,            // [NCHUNK][S][D]
                           int* __restrict__ sumr)
{
    __shared__ short pb[4 * 16 * LDP];
    __shared__ int red[4];

    const int tid  = threadIdx.x;
    const int w    = tid >> 6;
    const int lane = tid & 63;
    const int quad = lane >> 4;
    const int n16  = lane & 15;

    const int ib  = blockIdx.x & 63;
    const int ic  = blockIdx.x >> 6;
    const int i0w = ib * 64 + w * 16;
    const int jbase = ic * JCHUNK;

    s16x8 aQ[2];
#pragma unroll
    for (int ks = 0; ks < 2; ++ks)
        aQ[ks] = *(const s16x8*)&Qbf[(size_t)(i0w + n16) * D + ks * 32 + quad * 8];

    float rr[4];
#pragma unroll
    for (int rg = 0; rg < 4; ++rg) rr[rg] = RR[i0w + quad * 4 + rg];

    f32x4 accO[4];
#pragma unroll
    for (int ds = 0; ds < 4; ++ds) accO[ds] = (f32x4){0.f, 0.f, 0.f, 0.f};

    float lsum = 0.f;                 // r are small integers; fp32 sum exact
    short* pw = pb + w * 16 * LDP;

    s16x8 kf[2][8];      // K-frags, double-buffered
    s16x8 vf[8];         // V-frags, single-buffered (in-tile latency slack)
    float ub[2][16];     // u values in C-layout positions, double-buffered

    // prefetch tile 0: K-frags + u
#pragma unroll
    for (int e = 0; e < 8; ++e) {
        const int cs = e >> 1, ks = e & 1;
        kf[0][e] = *(const s16x8*)&Kbf[(size_t)(jbase + cs * 16 + n16) * D + ks * 32 + quad * 8];
    }
#pragma unroll
    for (int e = 0; e < 16; ++e) {
        const int cs = e >> 2, rg = e & 3;
        ub[0][e] = __builtin_nontemporal_load(
            &Ud[(size_t)(i0w + quad * 4 + rg) * S + jbase + cs * 16 + n16]);
    }

#pragma unroll
    for (int jt = 0; jt < NTILES; ++jt) {
        const int bu = jt & 1;
        const int j0 = jbase + jt * 64;

        // V-frags for THIS tile (consumed at tile end — in-tile slack hides them)
#pragma unroll
        for (int e = 0; e < 8; ++e) {
            const int ksj = e >> 2, ds = e & 3;
            vf[e] = *(const s16x8*)&VTbf[(size_t)(ds * 16 + n16) * S + j0 + ksj * 32 + quad * 8];
        }

        // next tile's K-frags + u
        if (jt + 1 < NTILES) {
            const int nb = (jt + 1) & 1;
            const int j1 = j0 + 64;
#pragma unroll
            for (int e = 0; e < 8; ++e) {
                const int cs = e >> 1, ks = e & 1;
                kf[nb][e] = *(const s16x8*)&Kbf[(size_t)(j1 + cs * 16 + n16) * D + ks * 32 + quad * 8];
            }
#pragma unroll
            for (int e = 0; e < 16; ++e) {
                const int cs = e >> 2, rg = e & 3;
                ub[nb][e] = __builtin_nontemporal_load(
                    &Ud[(size_t)(i0w + quad * 4 + rg) * S + j1 + cs * 16 + n16]);
            }
        }

        // QK^T on current K buffer
        f32x4 accqk[4];
#pragma unroll
        for (int cs = 0; cs < 4; ++cs) {
            f32x4 acc = (f32x4){0.f, 0.f, 0.f, 0.f};
#pragma unroll
            for (int ks = 0; ks < 2; ++ks)
                acc = __builtin_amdgcn_mfma_f32_16x16x32_bf16(aQ[ks], kf[bu][cs * 2 + ks], acc, 0, 0, 0);
            accqk[cs] = acc;
        }

        // epilogue: dropout (direct u compare) + floor mask; p -> wave-private LDS
#pragma unroll
        for (int cs = 0; cs < 4; ++cs) {
#pragma unroll
            for (int rg = 0; rg < 4; ++rg) {
                const float t = (ub[bu][cs * 4 + rg] >= 0.1f) ? accqk[cs][rg] : 0.0f;
                const float r = floorf(t * rr[rg]);
                lsum += r;
                pw[(quad * 4 + rg) * LDP + cs * 16 + n16] = (short)f2bf(t * r);
            }
        }

        __builtin_amdgcn_wave_barrier();
        __asm__ volatile("s_waitcnt lgkmcnt(0)" ::: "memory");
        __builtin_amdgcn_wave_barrier();

        // PV
#pragma unroll
        for (int ksj = 0; ksj < 2; ++ksj) {
            s16x8 aP = *(const s16x8*)&pw[n16 * LDP + ksj * 32 + quad * 8];
#pragma unroll
            for (int ds = 0; ds < 4; ++ds)
                accO[ds] = __builtin_amdgcn_mfma_f32_16x16x32_bf16(aP, vf[ksj * 4 + ds], accO[ds], 0, 0, 0);
        }
        __builtin_amdgcn_wave_barrier();   // pb reuse fence
    }

    // deterministic partial stores (full 64B segments)
    float* op = Opart + (size_t)ic * S * D;
#pragma unroll
    for (int ds = 0; ds < 4; ++ds) {
        const int d = ds * 16 + n16;
#pragma unroll
        for (int rg = 0; rg < 4; ++rg) {
            const int i = i0w + quad * 4 + rg;
            op[(size_t)i * D + d] = accO[ds][rg];
        }
    }

    // sum(r): wave shuffle -> LDS -> one int atomic per block
    for (int off = 32; off; off >>= 1) lsum += __shfl_down(lsum, off);
    if (lane == 0) red[w] = (int)lsum;
    __syncthreads();
    if (tid == 0) atomicAdd(sumr, red[0] + red[1] + red[2] + red[3]);
}

// ---- reduce partials over NCHUNK + apply 1/R ----
__global__ void reduce_out(const float* __restrict__ Opart,
                           const int* __restrict__ sumr,
                           float* __restrict__ out) {
    const int idx = blockIdx.x * 256 + threadIdx.x;   // 65536 float4 groups
    const float invR = 1.0f / (float)(*sumr);         // |R| < 2^24: exact
    float sx = 0.f, sy = 0.f, sz = 0.f, sw = 0.f;
#pragma unroll
    for (int c = 0; c < NCHUNK; ++c) {
        const float4 v = ((const float4*)(Opart + (size_t)c * S * D))[idx];
        sx += v.x; sy += v.y; sz += v.z; sw += v.w;
    }
    float4 o; o.x = sx * invR; o.y = sy * invR; o.z = sz * invR; o.w = sw * invR;
    ((float4*)out)[idx] = o;
}

extern "C" void kernel_launch(void* const* d_in, const int* in_sizes, int n_in,
                              void* d_out, int out_size, void* d_ws, size_t ws_size,
                              hipStream_t stream) {
    (void)in_sizes; (void)n_in; (void)out_size; (void)ws_size;
    const float* Q  = (const float*)d_in[0];
    const float* Kf = (const float*)d_in[1];
    const float* V  = (const float*)d_in[2];
    const float* Ud = (const float*)d_in[3];
    const float* RR = (const float*)d_in[4];
    float* out = (float*)d_out;

    // ws layout: Opart 16MB | Qbf 512KB | Kbf 512KB | VTbf 512KB | sumr
    char* ws = (char*)d_ws;
    float* Opart = (float*)ws;                                  // 16 MB
    short* Qbf  = (short*)(ws + (16u << 20));
    short* Kbf  = (short*)(ws + (16u << 20) + (512u << 10));
    short* VTbf = (short*)(ws + (16u << 20) + (1024u << 10));
    int*   sumr = (int*)  (ws + (16u << 20) + (1536u << 10));

    prep_all<<<dim3(576), dim3(256), 0, stream>>>(Q, Kf, V, Qbf, Kbf, VTbf, sumr);
    fused_main<<<dim3(64 * NCHUNK), dim3(256), 0, stream>>>(
        Qbf, Kbf, VTbf, Ud, RR, Opart, sumr);
    reduce_out<<<dim3(256), dim3(256), 0, stream>>>(Opart, sumr, out);
}